// Round 6
// baseline (271.175 us; speedup 1.0000x reference)
//
#include <hip/hip_runtime.h>
#include <hip/hip_fp16.h>

#define NB    32
#define NMAPS 1024
#define FDIM  512
#define NPOOL 256

typedef short  bf16x8 __attribute__((ext_vector_type(8)));
typedef float  f32x4  __attribute__((ext_vector_type(4)));

// f32 -> bf16 round-to-nearest-even
__device__ __forceinline__ unsigned short f2bf(float f) {
  unsigned int u = __float_as_uint(f);
  return (unsigned short)((u + 0x7fffu + ((u >> 16) & 1u)) >> 16);
}

// 16B-chunk XOR swizzle within a 1024-word row (256 chunks); involution.
__device__ __forceinline__ int swz(int c) { return c ^ ((c >> 3) & 7); }

// exact ranks: round(1 + o*1022/255) = (765 + 2044*o) / 510  (integer div)
__device__ __forceinline__ int rank_of(int o) { return (765 + 2044 * o) / 510; }

// packed f16x2 min/max via gfx950 v_pk_min_f16 / v_pk_max_f16 (header lacks
// __hmin2/__hmax2 device overloads on ROCm 7.2)
__device__ __forceinline__ unsigned pk_min(unsigned a, unsigned b) {
  unsigned r;
  asm("v_pk_min_f16 %0, %1, %2" : "=v"(r) : "v"(a), "v"(b));
  return r;
}
__device__ __forceinline__ unsigned pk_max(unsigned a, unsigned b) {
  unsigned r;
  asm("v_pk_max_f16 %0, %1, %2" : "=v"(r) : "v"(a), "v"(b));
  return r;
}

// ---------------- convert to FRAGMENT-MAJOR bf16 layout:
// Xp chunk index (((b*64+g)*64+kc)*16+li)*8+e  holds  X[b][16g+li][8kc+e]
__global__ __launch_bounds__(256) void convert_perm_kernel(const float* __restrict__ x,
                                                           unsigned short* __restrict__ xp) {
  const int T  = blockIdx.x * 256 + threadIdx.x;  // (b,g,kc,li)
  const int li = T & 15;
  const int kc = (T >> 4) & 63;
  const int g  = (T >> 10) & 63;
  const int b  = T >> 16;
  const float* src = x + ((size_t)((b * 64 + g) * 16 + li) * FDIM + kc * 8);
  const float4 p = *(const float4*)src;
  const float4 q = *(const float4*)(src + 4);
  uint4 o;
  o.x = (unsigned)f2bf(p.x) | ((unsigned)f2bf(p.y) << 16);
  o.y = (unsigned)f2bf(p.z) | ((unsigned)f2bf(p.w) << 16);
  o.z = (unsigned)f2bf(q.x) | ((unsigned)f2bf(q.y) << 16);
  o.w = (unsigned)f2bf(q.z) | ((unsigned)f2bf(q.w) << 16);
  *(uint4*)(xp + (size_t)T * 8) = o;
}

// ---------------- GEMM: 128x128 tile, 4 waves (2x2), coalesced fragment loads.
// Output: f16-PACKED row pairs  Cp[p*1024+col] = {hi=f16 C[2p+1][col], lo=f16 C[2p][col]}
__global__ __launch_bounds__(256, 4) void gemm_kernel(const unsigned short* __restrict__ xp,
                                                      unsigned* __restrict__ Cp) {
  const int bid = blockIdx.x;
  const int wk  = (bid & 7) * 256 + (bid >> 3);
  const int b   = wk >> 6;
  const int t   = wk & 63;
  const int ti  = t >> 3, tj = t & 7;

  const int tid  = threadIdx.x;
  const int lane = tid & 63;
  const int wr   = (tid >> 6) & 1;
  const int wc   = (tid >> 7) & 1;

  const unsigned short* __restrict__ Xp = xp + (size_t)b * (NMAPS * FDIM);
  const int gA0 = 8 * ti + 4 * wr;
  const int gB0 = 8 * tj + 4 * wc;

  f32x4 acc[4][4];
#pragma unroll
  for (int a = 0; a < 4; ++a)
#pragma unroll
    for (int n = 0; n < 4; ++n) acc[a][n] = (f32x4){0.f, 0.f, 0.f, 0.f};

  const unsigned short* pA = Xp + (size_t)gA0 * (64 * 128) + lane * 8;
  const unsigned short* pB = Xp + (size_t)gB0 * (64 * 128) + lane * 8;

  for (int kc0 = 0; kc0 < 64; kc0 += 4) {   // K step 32
    bf16x8 A[4], B[4];
#pragma unroll
    for (int a = 0; a < 4; ++a) A[a] = *(const bf16x8*)(pA + a * (64 * 128) + kc0 * 128);
#pragma unroll
    for (int n = 0; n < 4; ++n) B[n] = *(const bf16x8*)(pB + n * (64 * 128) + kc0 * 128);
#pragma unroll
    for (int a = 0; a < 4; ++a)
#pragma unroll
      for (int n = 0; n < 4; ++n)
        acc[a][n] = __builtin_amdgcn_mfma_f32_16x16x32_bf16(A[a], B[n], acc[a][n], 0, 0, 0);
  }

  // C/D layout: col = lane&15, row = (lane>>4)*4 + reg. regs r=0..3 are 4
  // consecutive rows of one column -> pack (r0,r1),(r2,r3) into f16x2 words.
  const int li = lane & 15, kh = lane >> 4;
  unsigned* __restrict__ Cb = Cp + (size_t)b * (512 * 1024);
#pragma unroll
  for (int a = 0; a < 4; ++a)
#pragma unroll
    for (int n = 0; n < 4; ++n) {
      const int col = 128 * tj + 64 * wc + 16 * n + li;
      const int p0  = (128 * ti + 64 * wr + 16 * a + 4 * kh) >> 1;  // even base /2
#pragma unroll
      for (int pr = 0; pr < 2; ++pr) {
        const float fl = acc[a][n][2 * pr]     * (1.0f / 512.0f);
        const float fh = acc[a][n][2 * pr + 1] * (1.0f / 512.0f);
        const unsigned wd = ((unsigned)__half_as_ushort(__float2half_rn(fh)) << 16)
                          |  (unsigned)__half_as_ushort(__float2half_rn(fl));
        Cb[(size_t)(p0 + pr) * 1024 + col] = wd;
      }
    }
}

// ---------------- sort + percentile gather on PACKED row pairs:
// each u32 register lane sorts TWO rows at once (f16x2 SIMD min/max).
// Wave: 4 rows (2 packed pairs, lane halves); block 256 thr = 16 rows.
__global__ __launch_bounds__(256) void sort_kernel(const unsigned* __restrict__ Cp,
                                                   float* __restrict__ out) {
  __shared__ unsigned buf[8 * 1024];   // 32 KiB
  const int tid  = threadIdx.x;
  const int lane = tid & 63;
  const int wv   = tid >> 6;
  const int ll   = lane & 31;        // lane within row-pair group
  const int h    = lane >> 5;
  const int rloc = wv * 2 + h;       // local row-pair 0..7
  const int bid  = blockIdx.x;
  const int wk   = (bid & 7) * 256 + (bid >> 3);   // match gemm's XCD mapping

  // load: element e = 32*ll + t of row-pair P
  unsigned v[32];
  {
    const unsigned* rp = Cp + ((size_t)wk * 8 + rloc) * 1024 + 32 * ll;
#pragma unroll
    for (int i = 0; i < 8; ++i) {
      const uint4 t4 = *(const uint4*)(rp + 4 * i);
      v[4 * i + 0] = t4.x; v[4 * i + 1] = t4.y;
      v[4 * i + 2] = t4.z; v[4 * i + 3] = t4.w;
    }
  }

  // descending bitonic sort of 1024 elems: take_min(e) = ((e&k)!=0)==((e&j)==0)
#pragma unroll
  for (int kb = 1; kb <= 10; ++kb) {
    const int k = 1 << kb;
#pragma unroll
    for (int jb = 9; jb >= 0; --jb) {
      if (jb >= kb) continue;        // folds at compile time
      const int j = 1 << jb;
      if (jb >= 5) {
        // cross-lane: partner ll ^ (j>>5)
        const int jl = j >> 5;
        const bool up = (ll & (k >> 5)) != 0;
        const bool tm = up == ((ll & jl) == 0);
#pragma unroll
        for (int t = 0; t < 32; ++t) {
          const unsigned o  = (unsigned)__shfl_xor((int)v[t], jl, 64);
          const unsigned mn = pk_min(v[t], o);
          const unsigned mx = pk_max(v[t], o);
          v[t] = tm ? mn : mx;
        }
      } else if (kb <= 4) {
        // in-lane, direction compile-time
#pragma unroll
        for (int t = 0; t < 32; ++t) {
          if (t & j) continue;
          const int u = t | j;
          const unsigned a0 = v[t], b0 = v[u];
          if ((t & k) != 0) { v[t] = pk_min(a0, b0); v[u] = pk_max(a0, b0); }
          else              { v[t] = pk_max(a0, b0); v[u] = pk_min(a0, b0); }
        }
      } else {
        // in-lane, direction uniform per lane
        const bool tm = (ll & (k >> 5)) != 0;
#pragma unroll
        for (int t = 0; t < 32; ++t) {
          if (t & j) continue;
          const int u = t | j;
          const unsigned a0 = v[t], b0 = v[u];
          const unsigned mn = pk_min(a0, b0), mx = pk_max(a0, b0);
          v[t] = tm ? mn : mx;
          v[u] = tm ? mx : mn;
        }
      }
    }
  }

  // dump sorted packed rows to LDS (swizzled 16B chunks)
  {
    unsigned* sb = buf + rloc * 1024;
#pragma unroll
    for (int i = 0; i < 8; ++i)
      *(uint4*)(sb + swz(8 * ll + i) * 4) =
          make_uint4(v[4 * i + 0], v[4 * i + 1], v[4 * i + 2], v[4 * i + 3]);
  }
  __syncthreads();

  // gather ranks: one u32 read serves BOTH rows of the pair
#pragma unroll
  for (int h2 = 0; h2 < 2; ++h2) {
    const int pl = wv * 2 + h2;
    const unsigned* sb2 = buf + pl * 1024;
    const size_t Pg = (size_t)wk * 8 + pl;
    float lo4[4], hi4[4];
#pragma unroll
    for (int q = 0; q < 4; ++q) {
      const int s = rank_of(4 * lane + q);
      const unsigned w32 = sb2[swz(s >> 2) * 4 + (s & 3)];
      lo4[q] = __half2float(__ushort_as_half((unsigned short)(w32 & 0xffffu)));
      hi4[q] = __half2float(__ushort_as_half((unsigned short)(w32 >> 16)));
    }
    *(float4*)(out + (2 * Pg) * 256 + 4 * lane) =
        make_float4(lo4[0], lo4[1], lo4[2], lo4[3]);
    *(float4*)(out + (2 * Pg + 1) * 256 + 4 * lane) =
        make_float4(hi4[0], hi4[1], hi4[2], hi4[3]);
  }
}

// ================= fallback fused kernel (used only if ws too small) =================
__device__ __forceinline__ bf16x8 ld_frag_f32(const float* p) {
  const float4 a = *(const float4*)p;
  const float4 b = *(const float4*)(p + 4);
  bf16x8 r;
  r[0] = (short)f2bf(a.x); r[1] = (short)f2bf(a.y);
  r[2] = (short)f2bf(a.z); r[3] = (short)f2bf(a.w);
  r[4] = (short)f2bf(b.x); r[5] = (short)f2bf(b.y);
  r[6] = (short)f2bf(b.z); r[7] = (short)f2bf(b.w);
  return r;
}

__device__ __forceinline__ int swz_ex(int row, int col) {
  return col ^ (((col >> 6) & 15) << 1) ^ (row & 1) ^ (((row >> 2) & 1) << 4);
}

__device__ __forceinline__ void sort1024_desc(float (&v)[64], const int li) {
#pragma unroll
  for (int kb = 1; kb <= 10; ++kb) {
    const int k = 1 << kb;
#pragma unroll
    for (int jb = 9; jb >= 0; --jb) {
      if (jb >= kb) continue;
      const int j = 1 << jb;
      if (jb >= 6) {
        const int jl = j >> 6;
        const bool up = (li & (k >> 6)) != 0;
        const bool tm = up == ((li & jl) == 0);
#pragma unroll
        for (int t = 0; t < 64; ++t) {
          const float o  = __shfl_xor(v[t], jl, 64);
          const float mn = fminf(v[t], o);
          const float mx = fmaxf(v[t], o);
          v[t] = tm ? mn : mx;
        }
      } else if (kb <= 5) {
#pragma unroll
        for (int t = 0; t < 64; ++t) {
          if (t & j) continue;
          const int u = t | j;
          const float a0 = v[t], b0 = v[u];
          if ((t & k) != 0) { v[t] = fminf(a0, b0); v[u] = fmaxf(a0, b0); }
          else              { v[t] = fmaxf(a0, b0); v[u] = fminf(a0, b0); }
        }
      } else {
        const bool tm = (li & (k >> 6)) != 0;
#pragma unroll
        for (int t = 0; t < 64; ++t) {
          if (t & j) continue;
          const int u = t | j;
          const float a0 = v[t], b0 = v[u];
          const float mn = fminf(a0, b0), mx = fmaxf(a0, b0);
          v[t] = tm ? mn : mx;
          v[u] = tm ? mx : mn;
        }
      }
    }
  }
}

__global__ __launch_bounds__(512) void corr_pool_kernel(const float* __restrict__ x,
                                                        float* __restrict__ out) {
  __shared__ float ex[16 * 1024];
  const int bid = blockIdx.x;
  const int xcd = bid & 7;
  const int idx = bid >> 3;
  const int b   = xcd + 8 * (idx >> 5);
  const int M0  = (idx & 31) * 32;

  const int tid  = threadIdx.x;
  const int lane = tid & 63;
  const int w    = tid >> 6;
  const int li   = lane & 15;
  const int kh   = lane >> 4;

  const float* __restrict__ Xf = x + (size_t)b * NMAPS * FDIM;

  f32x4 acc[2][8];
#pragma unroll
  for (int a = 0; a < 2; ++a)
#pragma unroll
    for (int n = 0; n < 8; ++n) acc[a][n] = (f32x4){0.f, 0.f, 0.f, 0.f};

#pragma unroll 2
  for (int k0 = 0; k0 < FDIM; k0 += 32) {
    bf16x8 A[2], B[8];
#pragma unroll
    for (int a = 0; a < 2; ++a)
      A[a] = ld_frag_f32(Xf + (M0 + 16 * a + li) * FDIM + k0 + kh * 8);
#pragma unroll
    for (int n = 0; n < 8; ++n)
      B[n] = ld_frag_f32(Xf + (128 * w + 16 * n + li) * FDIM + k0 + kh * 8);
#pragma unroll
    for (int a = 0; a < 2; ++a)
#pragma unroll
      for (int n = 0; n < 8; ++n)
        acc[a][n] = __builtin_amdgcn_mfma_f32_16x16x32_bf16(A[a], B[n], acc[a][n], 0, 0, 0);
  }

  const int R = 4 * w + kh;
  float v[64];
#pragma unroll
  for (int p = 0; p < 2; ++p) {
#pragma unroll
    for (int n = 0; n < 8; ++n) {
      const int col = 128 * w + 16 * n + li;
#pragma unroll
      for (int r = 0; r < 4; ++r) {
        const int rw = 16 * p + 4 * kh + r;
        ex[(rw & 15) * 1024 + swz_ex(rw, col)] = acc[p][n][r] * (1.0f / FDIM);
      }
    }
    __syncthreads();
    if ((w >> 2) == p) {
#pragma unroll
      for (int t = 0; t < 64; ++t)
        v[t] = ex[(R & 15) * 1024 + swz_ex(R, 64 * li + t)];
    }
    __syncthreads();
  }

  sort1024_desc(v, li);

  __syncthreads();
#pragma unroll
  for (int gp = 0; gp < 2; ++gp) {
    if ((w >> 2) == gp) {
#pragma unroll
      for (int t = 0; t < 64; ++t)
        ex[(R & 15) * 1024 + swz_ex(R, 64 * li + t)] = v[t];
    }
    __syncthreads();
    if ((w >> 2) == gp) {
#pragma unroll
      for (int rp = 0; rp < 4; ++rp) {
        const int Rr = 4 * w + rp;
        float ov[4];
#pragma unroll
        for (int q = 0; q < 4; ++q) {
          const int s = rank_of(4 * lane + q);
          ov[q] = ex[(Rr & 15) * 1024 + swz_ex(Rr, s)];
        }
        float* op = out + (size_t)(b * NMAPS + M0 + Rr) * NPOOL;
        *(float4*)(op + 4 * lane) = make_float4(ov[0], ov[1], ov[2], ov[3]);
      }
    }
    __syncthreads();
  }
}

extern "C" void kernel_launch(void* const* d_in, const int* in_sizes, int n_in,
                              void* d_out, int out_size, void* d_ws, size_t ws_size,
                              hipStream_t stream) {
  const float* x = (const float*)d_in[0];
  float* out = (float*)d_out;
  const size_t bf16_bytes  = (size_t)NB * NMAPS * FDIM * sizeof(unsigned short);  // 32 MiB
  const size_t cp16_bytes  = (size_t)NB * 512 * 1024 * sizeof(unsigned);          // 64 MiB

  if (ws_size >= bf16_bytes + cp16_bytes) {
    unsigned short* xp = (unsigned short*)d_ws;
    unsigned* Cp = (unsigned*)((char*)d_ws + bf16_bytes);
    convert_perm_kernel<<<dim3((NB * NMAPS * FDIM) / (256 * 8)), dim3(256), 0, stream>>>(x, xp);
    gemm_kernel<<<dim3(NB * 64), dim3(256), 0, stream>>>(xp, Cp);
    sort_kernel<<<dim3(NB * NMAPS / 16), dim3(256), 0, stream>>>(Cp, out);
  } else {
    corr_pool_kernel<<<dim3(NB * 32), dim3(512), 0, stream>>>(x, out);
  }
}

// Round 7
// 178.998 us; speedup vs baseline: 1.5150x; 1.5150x over previous
//
#include <hip/hip_runtime.h>

#define NB    32
#define NMAPS 1024
#define FDIM  512
#define NPOOL 256

typedef short  bf16x8 __attribute__((ext_vector_type(8)));
typedef float  f32x4  __attribute__((ext_vector_type(4)));

// f32 -> bf16 round-to-nearest-even
__device__ __forceinline__ unsigned short f2bf(float f) {
  unsigned int u = __float_as_uint(f);
  return (unsigned short)((u + 0x7fffu + ((u >> 16) & 1u)) >> 16);
}

// 16B-chunk XOR swizzle within a 1024-float row (256 chunks); involution.
__device__ __forceinline__ int swz(int c) { return c ^ ((c >> 3) & 7); }

// exact ranks: round(1 + o*1022/255) = (765 + 2044*o) / 510  (integer div)
__device__ __forceinline__ int rank_of(int o) { return (765 + 2044 * o) / 510; }

// ---------------- convert to FRAGMENT-MAJOR bf16 layout:
// Xp chunk index (((b*64+g)*64+kc)*16+li)*8+e  holds  X[b][16g+li][8kc+e]
__global__ __launch_bounds__(256) void convert_perm_kernel(const float* __restrict__ x,
                                                           unsigned short* __restrict__ xp) {
  const int T  = blockIdx.x * 256 + threadIdx.x;  // (b,g,kc,li)
  const int li = T & 15;
  const int kc = (T >> 4) & 63;
  const int g  = (T >> 10) & 63;
  const int b  = T >> 16;
  const float* src = x + ((size_t)((b * 64 + g) * 16 + li) * FDIM + kc * 8);
  const float4 p = *(const float4*)src;
  const float4 q = *(const float4*)(src + 4);
  uint4 o;
  o.x = (unsigned)f2bf(p.x) | ((unsigned)f2bf(p.y) << 16);
  o.y = (unsigned)f2bf(p.z) | ((unsigned)f2bf(p.w) << 16);
  o.z = (unsigned)f2bf(q.x) | ((unsigned)f2bf(q.y) << 16);
  o.w = (unsigned)f2bf(q.z) | ((unsigned)f2bf(q.w) << 16);
  *(uint4*)(xp + (size_t)T * 8) = o;
}

// ---------------- proven round-4 descending bitonic network:
// row spread over 32 lanes (ll), 32 elems/lane; element e = 32*ll + t.
// take_min(e) = ((e&k)!=0) == ((e&j)==0)
__device__ __forceinline__ void sort32(float (&v)[32], const int ll) {
#pragma unroll
  for (int kb = 1; kb <= 10; ++kb) {
    const int k = 1 << kb;
#pragma unroll
    for (int jb = 9; jb >= 0; --jb) {
      if (jb >= kb) continue;        // folds at compile time
      const int j = 1 << jb;
      if (jb >= 5) {
        const int jl = j >> 5;
        const bool up = (ll & (k >> 5)) != 0;
        const bool tm = up == ((ll & jl) == 0);
#pragma unroll
        for (int t = 0; t < 32; ++t) {
          const float o  = __shfl_xor(v[t], jl, 64);
          const float mn = fminf(v[t], o);
          const float mx = fmaxf(v[t], o);
          v[t] = tm ? mn : mx;
        }
      } else if (kb <= 4) {
#pragma unroll
        for (int t = 0; t < 32; ++t) {
          if (t & j) continue;
          const int u = t | j;
          const float a0 = v[t], b0 = v[u];
          if ((t & k) != 0) { v[t] = fminf(a0, b0); v[u] = fmaxf(a0, b0); }
          else              { v[t] = fmaxf(a0, b0); v[u] = fminf(a0, b0); }
        }
      } else {
        const bool tm = (ll & (k >> 5)) != 0;
#pragma unroll
        for (int t = 0; t < 32; ++t) {
          if (t & j) continue;
          const int u = t | j;
          const float a0 = v[t], b0 = v[u];
          const float mn = fminf(a0, b0), mx = fmaxf(a0, b0);
          v[t] = tm ? mn : mx;
          v[u] = tm ? mx : mn;
        }
      }
    }
  }
}

// ---------------- FUSED: GEMM(32x1024 tile, MFMA) -> LDS exchange -> sort -> ranks
__global__ __launch_bounds__(512, 4) void fused_kernel(const unsigned short* __restrict__ xp,
                                                       float* __restrict__ out) {
  __shared__ float ex[16 * 1024];   // 64 KiB -> 2 blocks/CU

  const int bid = blockIdx.x;                    // 1024 blocks
  const int wk  = (bid & 7) * 128 + (bid >> 3);  // bijective XCD swizzle
  const int b   = wk >> 5;                       // batch: 4 per XCD
  const int mt  = wk & 31;
  const int M0  = mt * 32;

  const int tid  = threadIdx.x;
  const int lane = tid & 63;
  const int w    = tid >> 6;      // 8 waves; wave owns cols [128w, 128w+128)
  const int li   = lane & 15;
  const int ll   = lane & 31;
  const int h    = lane >> 5;
  const int kh   = lane >> 4;
  const int rloc = 2 * w + h;     // ex row this lane sorts (0..15)

  const unsigned short* __restrict__ Xp = xp + (size_t)b * (NMAPS * FDIM);

  // ================= GEMM phase (validated round-3 structure) =================
  f32x4 acc0[8], acc1[8];         // row-groups 2mt (rows 0..15), 2mt+1 (16..31)
#pragma unroll
  for (int n = 0; n < 8; ++n) {
    acc0[n] = (f32x4){0.f, 0.f, 0.f, 0.f};
    acc1[n] = (f32x4){0.f, 0.f, 0.f, 0.f};
  }

  const unsigned short* pA = Xp + (size_t)(2 * mt) * 8192 + lane * 8;  // 8192 = 16*512
  const unsigned short* pB = Xp + (size_t)(8 * w) * 8192 + lane * 8;

  for (int kc0 = 0; kc0 < 64; kc0 += 4) {   // K step 32 (4 chunks of 8)
    const bf16x8 A0 = *(const bf16x8*)(pA + kc0 * 128);
    const bf16x8 A1 = *(const bf16x8*)(pA + 8192 + kc0 * 128);
#pragma unroll
    for (int half = 0; half < 2; ++half) {   // limit live B-frags to 4
      bf16x8 B[4];
#pragma unroll
      for (int n = 0; n < 4; ++n)
        B[n] = *(const bf16x8*)(pB + (size_t)(4 * half + n) * 8192 + kc0 * 128);
#pragma unroll
      for (int n = 0; n < 4; ++n) {
        if (half == 0) {
          acc0[n] = __builtin_amdgcn_mfma_f32_16x16x32_bf16(A0, B[n], acc0[n], 0, 0, 0);
          acc1[n] = __builtin_amdgcn_mfma_f32_16x16x32_bf16(A1, B[n], acc1[n], 0, 0, 0);
        } else {
          acc0[4 + n] = __builtin_amdgcn_mfma_f32_16x16x32_bf16(A0, B[n], acc0[4 + n], 0, 0, 0);
          acc1[4 + n] = __builtin_amdgcn_mfma_f32_16x16x32_bf16(A1, B[n], acc1[4 + n], 0, 0, 0);
        }
      }
    }
  }

  // ================= exchange phase =================
  // C/D layout (validated r2-r4): value acc[n][r] is C[local 16a+4kh+r][128w+16n+li]
  float v0[32], v1[32];

  // ---- phase 0: rows 0..15
#pragma unroll
  for (int n = 0; n < 8; ++n) {
    const int cw = 32 * w + 4 * n + (li >> 2);   // 16B chunk of col
    const int q  = li & 3;
#pragma unroll
    for (int r = 0; r < 4; ++r)
      ex[(4 * kh + r) * 1024 + swz(cw) * 4 + q] = acc0[n][r] * (1.0f / 512.0f);
  }
  __syncthreads();
#pragma unroll
  for (int i = 0; i < 8; ++i) {
    const float4 t4 = *(const float4*)(ex + rloc * 1024 + swz(8 * ll + i) * 4);
    v0[4 * i + 0] = t4.x; v0[4 * i + 1] = t4.y;
    v0[4 * i + 2] = t4.z; v0[4 * i + 3] = t4.w;
  }
  __syncthreads();

  // ---- phase 1: rows 16..31
#pragma unroll
  for (int n = 0; n < 8; ++n) {
    const int cw = 32 * w + 4 * n + (li >> 2);
    const int q  = li & 3;
#pragma unroll
    for (int r = 0; r < 4; ++r)
      ex[(4 * kh + r) * 1024 + swz(cw) * 4 + q] = acc1[n][r] * (1.0f / 512.0f);
  }
  __syncthreads();
#pragma unroll
  for (int i = 0; i < 8; ++i) {
    const float4 t4 = *(const float4*)(ex + rloc * 1024 + swz(8 * ll + i) * 4);
    v1[4 * i + 0] = t4.x; v1[4 * i + 1] = t4.y;
    v1[4 * i + 2] = t4.z; v1[4 * i + 3] = t4.w;
  }
  // no further barriers: each wave now only touches ex rows 2w, 2w+1 (own region)

  // ================= sort + rank gather, phase 0 rows =================
  sort32(v0, ll);
#pragma unroll
  for (int i = 0; i < 8; ++i)
    *(float4*)(ex + rloc * 1024 + swz(8 * ll + i) * 4) =
        make_float4(v0[4 * i + 0], v0[4 * i + 1], v0[4 * i + 2], v0[4 * i + 3]);
#pragma unroll
  for (int h2 = 0; h2 < 2; ++h2) {
    const float* sb = ex + (2 * w + h2) * 1024;
    float ov[4];
#pragma unroll
    for (int q = 0; q < 4; ++q) {
      const int s = rank_of(4 * lane + q);
      ov[q] = sb[swz(s >> 2) * 4 + (s & 3)];
    }
    *(float4*)(out + ((size_t)b * NMAPS + M0 + 2 * w + h2) * NPOOL + 4 * lane) =
        make_float4(ov[0], ov[1], ov[2], ov[3]);
  }

  // ================= sort + rank gather, phase 1 rows =================
  sort32(v1, ll);
#pragma unroll
  for (int i = 0; i < 8; ++i)
    *(float4*)(ex + rloc * 1024 + swz(8 * ll + i) * 4) =
        make_float4(v1[4 * i + 0], v1[4 * i + 1], v1[4 * i + 2], v1[4 * i + 3]);
#pragma unroll
  for (int h2 = 0; h2 < 2; ++h2) {
    const float* sb = ex + (2 * w + h2) * 1024;
    float ov[4];
#pragma unroll
    for (int q = 0; q < 4; ++q) {
      const int s = rank_of(4 * lane + q);
      ov[q] = sb[swz(s >> 2) * 4 + (s & 3)];
    }
    *(float4*)(out + ((size_t)b * NMAPS + M0 + 16 + 2 * w + h2) * NPOOL + 4 * lane) =
        make_float4(ov[0], ov[1], ov[2], ov[3]);
  }
}

// ================= fallback fused kernel (used only if ws too small) =================
__device__ __forceinline__ bf16x8 ld_frag_f32(const float* p) {
  const float4 a = *(const float4*)p;
  const float4 b = *(const float4*)(p + 4);
  bf16x8 r;
  r[0] = (short)f2bf(a.x); r[1] = (short)f2bf(a.y);
  r[2] = (short)f2bf(a.z); r[3] = (short)f2bf(a.w);
  r[4] = (short)f2bf(b.x); r[5] = (short)f2bf(b.y);
  r[6] = (short)f2bf(b.z); r[7] = (short)f2bf(b.w);
  return r;
}

__device__ __forceinline__ int swz_ex(int row, int col) {
  return col ^ (((col >> 6) & 15) << 1) ^ (row & 1) ^ (((row >> 2) & 1) << 4);
}

__device__ __forceinline__ void sort1024_desc(float (&v)[64], const int li) {
#pragma unroll
  for (int kb = 1; kb <= 10; ++kb) {
    const int k = 1 << kb;
#pragma unroll
    for (int jb = 9; jb >= 0; --jb) {
      if (jb >= kb) continue;
      const int j = 1 << jb;
      if (jb >= 6) {
        const int jl = j >> 6;
        const bool up = (li & (k >> 6)) != 0;
        const bool tm = up == ((li & jl) == 0);
#pragma unroll
        for (int t = 0; t < 64; ++t) {
          const float o  = __shfl_xor(v[t], jl, 64);
          const float mn = fminf(v[t], o);
          const float mx = fmaxf(v[t], o);
          v[t] = tm ? mn : mx;
        }
      } else if (kb <= 5) {
#pragma unroll
        for (int t = 0; t < 64; ++t) {
          if (t & j) continue;
          const int u = t | j;
          const float a0 = v[t], b0 = v[u];
          if ((t & k) != 0) { v[t] = fminf(a0, b0); v[u] = fmaxf(a0, b0); }
          else              { v[t] = fmaxf(a0, b0); v[u] = fminf(a0, b0); }
        }
      } else {
        const bool tm = (li & (k >> 6)) != 0;
#pragma unroll
        for (int t = 0; t < 64; ++t) {
          if (t & j) continue;
          const int u = t | j;
          const float a0 = v[t], b0 = v[u];
          const float mn = fminf(a0, b0), mx = fmaxf(a0, b0);
          v[t] = tm ? mn : mx;
          v[u] = tm ? mx : mn;
        }
      }
    }
  }
}

__global__ __launch_bounds__(512) void corr_pool_kernel(const float* __restrict__ x,
                                                        float* __restrict__ out) {
  __shared__ float ex[16 * 1024];
  const int bid = blockIdx.x;
  const int xcd = bid & 7;
  const int idx = bid >> 3;
  const int b   = xcd + 8 * (idx >> 5);
  const int M0  = (idx & 31) * 32;

  const int tid  = threadIdx.x;
  const int lane = tid & 63;
  const int w    = tid >> 6;
  const int li   = lane & 15;
  const int kh   = lane >> 4;

  const float* __restrict__ Xf = x + (size_t)b * NMAPS * FDIM;

  f32x4 acc[2][8];
#pragma unroll
  for (int a = 0; a < 2; ++a)
#pragma unroll
    for (int n = 0; n < 8; ++n) acc[a][n] = (f32x4){0.f, 0.f, 0.f, 0.f};

#pragma unroll 2
  for (int k0 = 0; k0 < FDIM; k0 += 32) {
    bf16x8 A[2], B[8];
#pragma unroll
    for (int a = 0; a < 2; ++a)
      A[a] = ld_frag_f32(Xf + (M0 + 16 * a + li) * FDIM + k0 + kh * 8);
#pragma unroll
    for (int n = 0; n < 8; ++n)
      B[n] = ld_frag_f32(Xf + (128 * w + 16 * n + li) * FDIM + k0 + kh * 8);
#pragma unroll
    for (int a = 0; a < 2; ++a)
#pragma unroll
      for (int n = 0; n < 8; ++n)
        acc[a][n] = __builtin_amdgcn_mfma_f32_16x16x32_bf16(A[a], B[n], acc[a][n], 0, 0, 0);
  }

  const int R = 4 * w + kh;
  float v[64];
#pragma unroll
  for (int p = 0; p < 2; ++p) {
#pragma unroll
    for (int n = 0; n < 8; ++n) {
      const int col = 128 * w + 16 * n + li;
#pragma unroll
      for (int r = 0; r < 4; ++r) {
        const int rw = 16 * p + 4 * kh + r;
        ex[(rw & 15) * 1024 + swz_ex(rw, col)] = acc[p][n][r] * (1.0f / FDIM);
      }
    }
    __syncthreads();
    if ((w >> 2) == p) {
#pragma unroll
      for (int t = 0; t < 64; ++t)
        v[t] = ex[(R & 15) * 1024 + swz_ex(R, 64 * li + t)];
    }
    __syncthreads();
  }

  sort1024_desc(v, li);

  __syncthreads();
#pragma unroll
  for (int gp = 0; gp < 2; ++gp) {
    if ((w >> 2) == gp) {
#pragma unroll
      for (int t = 0; t < 64; ++t)
        ex[(R & 15) * 1024 + swz_ex(R, 64 * li + t)] = v[t];
    }
    __syncthreads();
    if ((w >> 2) == gp) {
#pragma unroll
      for (int rp = 0; rp < 4; ++rp) {
        const int Rr = 4 * w + rp;
        float ov[4];
#pragma unroll
        for (int q = 0; q < 4; ++q) {
          const int s = rank_of(4 * lane + q);
          ov[q] = ex[(Rr & 15) * 1024 + swz_ex(Rr, s)];
        }
        float* op = out + (size_t)(b * NMAPS + M0 + Rr) * NPOOL;
        *(float4*)(op + 4 * lane) = make_float4(ov[0], ov[1], ov[2], ov[3]);
      }
    }
    __syncthreads();
  }
}

extern "C" void kernel_launch(void* const* d_in, const int* in_sizes, int n_in,
                              void* d_out, int out_size, void* d_ws, size_t ws_size,
                              hipStream_t stream) {
  const float* x = (const float*)d_in[0];
  float* out = (float*)d_out;
  const size_t bf16_bytes = (size_t)NB * NMAPS * FDIM * sizeof(unsigned short);  // 32 MiB

  if (ws_size >= bf16_bytes) {
    unsigned short* xp = (unsigned short*)d_ws;
    convert_perm_kernel<<<dim3((NB * NMAPS * FDIM) / (256 * 8)), dim3(256), 0, stream>>>(x, xp);
    fused_kernel<<<dim3(NB * 32), dim3(512), 0, stream>>>(xp, out);
  } else {
    corr_pool_kernel<<<dim3(NB * 32), dim3(512), 0, stream>>>(x, out);
  }
}

// Round 10
// 168.953 us; speedup vs baseline: 1.6050x; 1.0595x over previous
//
#include <hip/hip_runtime.h>

#define NB    32
#define NMAPS 1024
#define FDIM  512
#define NPOOL 256

typedef short  bf16x8 __attribute__((ext_vector_type(8)));
typedef float  f32x4  __attribute__((ext_vector_type(4)));

// f32 -> bf16 round-to-nearest-even
__device__ __forceinline__ unsigned short f2bf(float f) {
  unsigned int u = __float_as_uint(f);
  return (unsigned short)((u + 0x7fffu + ((u >> 16) & 1u)) >> 16);
}

// 16B-chunk XOR swizzle within a 1024-float row (256 chunks); involution.
__device__ __forceinline__ int swz(int c) { return c ^ ((c >> 3) & 7); }

// exact ranks: round(1 + o*1022/255) = (765 + 2044*o) / 510  (integer div)
__device__ __forceinline__ int rank_of(int o) { return (765 + 2044 * o) / 510; }

// ---------------- convert to FRAGMENT-MAJOR bf16 layout:
// Xp chunk index (((b*64+g)*64+kc)*16+li)*8+e  holds  X[b][16g+li][8kc+e]
__global__ __launch_bounds__(256) void convert_perm_kernel(const float* __restrict__ x,
                                                           unsigned short* __restrict__ xp) {
  const int T  = blockIdx.x * 256 + threadIdx.x;  // (b,g,kc,li)
  const int li = T & 15;
  const int kc = (T >> 4) & 63;
  const int g  = (T >> 10) & 63;
  const int b  = T >> 16;
  const float* src = x + ((size_t)((b * 64 + g) * 16 + li) * FDIM + kc * 8);
  const float4 p = *(const float4*)src;
  const float4 q = *(const float4*)(src + 4);
  uint4 o;
  o.x = (unsigned)f2bf(p.x) | ((unsigned)f2bf(p.y) << 16);
  o.y = (unsigned)f2bf(p.z) | ((unsigned)f2bf(p.w) << 16);
  o.z = (unsigned)f2bf(q.x) | ((unsigned)f2bf(q.y) << 16);
  o.w = (unsigned)f2bf(q.z) | ((unsigned)f2bf(q.w) << 16);
  *(uint4*)(xp + (size_t)T * 8) = o;
}

// ---------------- descending bitonic sort, round-7 geometry (e = 32*ll + t,
// ll = lane&31, 32 elems/lane), with sign-flip encoding for levels k>=32:
// w = v ^ sign where up=(ll&(k>>5))!=0. In encoded space every in-lane pair
// is (low=max, high=min) and cross CEs are (low lane keeps max, high min).
// Cross-lane primitive: __shfl_xor (hardware-proven rounds 1-7).
__device__ __forceinline__ void sort32e(float (&v)[32], const int ll) {
  // ---- levels kb=1..4: in-lane, directions compile-time (e&k = t&k)
#pragma unroll
  for (int kb = 1; kb <= 4; ++kb) {
    const int k = 1 << kb;
#pragma unroll
    for (int jb = 3; jb >= 0; --jb) {
      if (jb >= kb) continue;                 // folds at compile time
      const int j = 1 << jb;
#pragma unroll
      for (int t = 0; t < 32; ++t) {
        if (t & j) continue;
        const int u = t | j;
        const float a0 = v[t], b0 = v[u];
        if ((t & k) != 0) { v[t] = fminf(a0, b0); v[u] = fmaxf(a0, b0); }
        else              { v[t] = fmaxf(a0, b0); v[u] = fminf(a0, b0); }
      }
    }
  }
  // ---- levels kb=5..10 with sign-flip encoding (delta-XOR between levels)
  unsigned curM = 0;
#pragma unroll
  for (int kb = 5; kb <= 10; ++kb) {
    const int k = 1 << kb;
    const unsigned m = (kb == 10) ? 0u : ((ll & (k >> 5)) ? 0x80000000u : 0u);
    const unsigned d = curM ^ m;
#pragma unroll
    for (int t = 0; t < 32; ++t)
      v[t] = __int_as_float(__float_as_int(v[t]) ^ (int)d);
    curM = m;
    // cross stages (jb=9..5, jb<kb): low lane keeps max_enc, high keeps min_enc
#pragma unroll
    for (int jb = 9; jb >= 5; --jb) {
      if (jb >= kb) continue;
      const int jl = 1 << (jb - 5);
      const bool high = (ll & jl) != 0;
#pragma unroll
      for (int t = 0; t < 32; ++t) {
        const float o  = __shfl_xor(v[t], jl, 64);
        const float mn = fminf(v[t], o);
        const float mx = fmaxf(v[t], o);
        v[t] = high ? mn : mx;
      }
    }
    // in-lane stages jb=4..0: uniform (low=max, high=min) in encoded space
#pragma unroll
    for (int jb = 4; jb >= 0; --jb) {
      const int j = 1 << jb;
#pragma unroll
      for (int t = 0; t < 32; ++t) {
        if (t & j) continue;
        const int u = t | j;
        const float a0 = v[t], b0 = v[u];
        v[t] = fmaxf(a0, b0);
        v[u] = fminf(a0, b0);
      }
    }
  }
  // curM == 0 after kb=10: values back in plain encoding.
}

// ---------------- FUSED: GEMM(32x1024 tile, MFMA) -> LDS exchange -> sort -> ranks
// (byte-identical to the round-7 passing kernel except sort32 -> sort32e)
__global__ __launch_bounds__(512, 4) void fused_kernel(const unsigned short* __restrict__ xp,
                                                       float* __restrict__ out) {
  __shared__ float ex[16 * 1024];   // 64 KiB -> 2 blocks/CU

  const int bid = blockIdx.x;                    // 1024 blocks
  const int wk  = (bid & 7) * 128 + (bid >> 3);  // bijective XCD swizzle
  const int b   = wk >> 5;                       // batch: 4 per XCD
  const int mt  = wk & 31;
  const int M0  = mt * 32;

  const int tid  = threadIdx.x;
  const int lane = tid & 63;
  const int w    = tid >> 6;      // 8 waves; wave owns cols [128w, 128w+128)
  const int li   = lane & 15;
  const int ll   = lane & 31;
  const int h    = lane >> 5;
  const int kh   = lane >> 4;
  const int rloc = 2 * w + h;     // ex row this lane sorts (0..15)

  const unsigned short* __restrict__ Xp = xp + (size_t)b * (NMAPS * FDIM);

  // ================= GEMM phase =================
  f32x4 acc0[8], acc1[8];         // local rows 0..15 / 16..31
#pragma unroll
  for (int n = 0; n < 8; ++n) {
    acc0[n] = (f32x4){0.f, 0.f, 0.f, 0.f};
    acc1[n] = (f32x4){0.f, 0.f, 0.f, 0.f};
  }

  const unsigned short* pA = Xp + (size_t)(2 * mt) * 8192 + lane * 8;  // 8192 = 16*512
  const unsigned short* pB = Xp + (size_t)(8 * w) * 8192 + lane * 8;

  for (int kc0 = 0; kc0 < 64; kc0 += 4) {   // K step 32 (4 chunks of 8)
    const bf16x8 A0 = *(const bf16x8*)(pA + kc0 * 128);
    const bf16x8 A1 = *(const bf16x8*)(pA + 8192 + kc0 * 128);
#pragma unroll
    for (int half = 0; half < 2; ++half) {   // limit live B-frags to 4
      bf16x8 B[4];
#pragma unroll
      for (int n = 0; n < 4; ++n)
        B[n] = *(const bf16x8*)(pB + (size_t)(4 * half + n) * 8192 + kc0 * 128);
#pragma unroll
      for (int n = 0; n < 4; ++n) {
        if (half == 0) {
          acc0[n] = __builtin_amdgcn_mfma_f32_16x16x32_bf16(A0, B[n], acc0[n], 0, 0, 0);
          acc1[n] = __builtin_amdgcn_mfma_f32_16x16x32_bf16(A1, B[n], acc1[n], 0, 0, 0);
        } else {
          acc0[4 + n] = __builtin_amdgcn_mfma_f32_16x16x32_bf16(A0, B[n], acc0[4 + n], 0, 0, 0);
          acc1[4 + n] = __builtin_amdgcn_mfma_f32_16x16x32_bf16(A1, B[n], acc1[4 + n], 0, 0, 0);
        }
      }
    }
  }

  // ================= exchange phase (round-7 proven) =================
  float v0[32], v1[32];

  // ---- phase 0: rows 0..15
#pragma unroll
  for (int n = 0; n < 8; ++n) {
    const int cw = 32 * w + 4 * n + (li >> 2);   // 16B chunk of col
    const int q  = li & 3;
#pragma unroll
    for (int r = 0; r < 4; ++r)
      ex[(4 * kh + r) * 1024 + swz(cw) * 4 + q] = acc0[n][r] * (1.0f / 512.0f);
  }
  __syncthreads();
#pragma unroll
  for (int i = 0; i < 8; ++i) {
    const float4 t4 = *(const float4*)(ex + rloc * 1024 + swz(8 * ll + i) * 4);
    v0[4 * i + 0] = t4.x; v0[4 * i + 1] = t4.y;
    v0[4 * i + 2] = t4.z; v0[4 * i + 3] = t4.w;
  }
  __syncthreads();

  // ---- phase 1: rows 16..31
#pragma unroll
  for (int n = 0; n < 8; ++n) {
    const int cw = 32 * w + 4 * n + (li >> 2);
    const int q  = li & 3;
#pragma unroll
    for (int r = 0; r < 4; ++r)
      ex[(4 * kh + r) * 1024 + swz(cw) * 4 + q] = acc1[n][r] * (1.0f / 512.0f);
  }
  __syncthreads();
#pragma unroll
  for (int i = 0; i < 8; ++i) {
    const float4 t4 = *(const float4*)(ex + rloc * 1024 + swz(8 * ll + i) * 4);
    v1[4 * i + 0] = t4.x; v1[4 * i + 1] = t4.y;
    v1[4 * i + 2] = t4.z; v1[4 * i + 3] = t4.w;
  }
  // no further barriers: each wave now only touches ex rows 2w, 2w+1 (own region)

  // ================= sort + rank gather, phase 0 rows =================
  sort32e(v0, ll);
#pragma unroll
  for (int i = 0; i < 8; ++i)
    *(float4*)(ex + rloc * 1024 + swz(8 * ll + i) * 4) =
        make_float4(v0[4 * i + 0], v0[4 * i + 1], v0[4 * i + 2], v0[4 * i + 3]);
#pragma unroll
  for (int h2 = 0; h2 < 2; ++h2) {
    const float* sb = ex + (2 * w + h2) * 1024;
    float ov[4];
#pragma unroll
    for (int q = 0; q < 4; ++q) {
      const int s = rank_of(4 * lane + q);
      ov[q] = sb[swz(s >> 2) * 4 + (s & 3)];
    }
    *(float4*)(out + ((size_t)b * NMAPS + M0 + 2 * w + h2) * NPOOL + 4 * lane) =
        make_float4(ov[0], ov[1], ov[2], ov[3]);
  }

  // ================= sort + rank gather, phase 1 rows =================
  sort32e(v1, ll);
#pragma unroll
  for (int i = 0; i < 8; ++i)
    *(float4*)(ex + rloc * 1024 + swz(8 * ll + i) * 4) =
        make_float4(v1[4 * i + 0], v1[4 * i + 1], v1[4 * i + 2], v1[4 * i + 3]);
#pragma unroll
  for (int h2 = 0; h2 < 2; ++h2) {
    const float* sb = ex + (2 * w + h2) * 1024;
    float ov[4];
#pragma unroll
    for (int q = 0; q < 4; ++q) {
      const int s = rank_of(4 * lane + q);
      ov[q] = sb[swz(s >> 2) * 4 + (s & 3)];
    }
    *(float4*)(out + ((size_t)b * NMAPS + M0 + 16 + 2 * w + h2) * NPOOL + 4 * lane) =
        make_float4(ov[0], ov[1], ov[2], ov[3]);
  }
}

// ================= fallback fused kernel (used only if ws too small) =================
__device__ __forceinline__ bf16x8 ld_frag_f32(const float* p) {
  const float4 a = *(const float4*)p;
  const float4 b = *(const float4*)(p + 4);
  bf16x8 r;
  r[0] = (short)f2bf(a.x); r[1] = (short)f2bf(a.y);
  r[2] = (short)f2bf(a.z); r[3] = (short)f2bf(a.w);
  r[4] = (short)f2bf(b.x); r[5] = (short)f2bf(b.y);
  r[6] = (short)f2bf(b.z); r[7] = (short)f2bf(b.w);
  return r;
}

__device__ __forceinline__ int swz_ex(int row, int col) {
  return col ^ (((col >> 6) & 15) << 1) ^ (row & 1) ^ (((row >> 2) & 1) << 4);
}

__device__ __forceinline__ void sort1024_desc(float (&v)[64], const int li) {
#pragma unroll
  for (int kb = 1; kb <= 10; ++kb) {
    const int k = 1 << kb;
#pragma unroll
    for (int jb = 9; jb >= 0; --jb) {
      if (jb >= kb) continue;
      const int j = 1 << jb;
      if (jb >= 6) {
        const int jl = j >> 6;
        const bool up = (li & (k >> 6)) != 0;
        const bool tm = up == ((li & jl) == 0);
#pragma unroll
        for (int t = 0; t < 64; ++t) {
          const float o  = __shfl_xor(v[t], jl, 64);
          const float mn = fminf(v[t], o);
          const float mx = fmaxf(v[t], o);
          v[t] = tm ? mn : mx;
        }
      } else if (kb <= 5) {
#pragma unroll
        for (int t = 0; t < 64; ++t) {
          if (t & j) continue;
          const int u = t | j;
          const float a0 = v[t], b0 = v[u];
          if ((t & k) != 0) { v[t] = fminf(a0, b0); v[u] = fmaxf(a0, b0); }
          else              { v[t] = fmaxf(a0, b0); v[u] = fminf(a0, b0); }
        }
      } else {
        const bool tm = (li & (k >> 6)) != 0;
#pragma unroll
        for (int t = 0; t < 64; ++t) {
          if (t & j) continue;
          const int u = t | j;
          const float a0 = v[t], b0 = v[u];
          const float mn = fminf(a0, b0), mx = fmaxf(a0, b0);
          v[t] = tm ? mn : mx;
          v[u] = tm ? mx : mn;
        }
      }
    }
  }
}

__global__ __launch_bounds__(512) void corr_pool_kernel(const float* __restrict__ x,
                                                        float* __restrict__ out) {
  __shared__ float ex[16 * 1024];
  const int bid = blockIdx.x;
  const int xcd = bid & 7;
  const int idx = bid >> 3;
  const int b   = xcd + 8 * (idx >> 5);
  const int M0  = (idx & 31) * 32;

  const int tid  = threadIdx.x;
  const int lane = tid & 63;
  const int w    = tid >> 6;
  const int li   = lane & 15;
  const int kh   = lane >> 4;

  const float* __restrict__ Xf = x + (size_t)b * NMAPS * FDIM;

  f32x4 acc[2][8];
#pragma unroll
  for (int a = 0; a < 2; ++a)
#pragma unroll
    for (int n = 0; n < 8; ++n) acc[a][n] = (f32x4){0.f, 0.f, 0.f, 0.f};

#pragma unroll 2
  for (int k0 = 0; k0 < FDIM; k0 += 32) {
    bf16x8 A[2], B[8];
#pragma unroll
    for (int a = 0; a < 2; ++a)
      A[a] = ld_frag_f32(Xf + (M0 + 16 * a + li) * FDIM + k0 + kh * 8);
#pragma unroll
    for (int n = 0; n < 8; ++n)
      B[n] = ld_frag_f32(Xf + (128 * w + 16 * n + li) * FDIM + k0 + kh * 8);
#pragma unroll
    for (int a = 0; a < 2; ++a)
#pragma unroll
      for (int n = 0; n < 8; ++n)
        acc[a][n] = __builtin_amdgcn_mfma_f32_16x16x32_bf16(A[a], B[n], acc[a][n], 0, 0, 0);
  }

  const int R = 4 * w + kh;
  float v[64];
#pragma unroll
  for (int p = 0; p < 2; ++p) {
#pragma unroll
    for (int n = 0; n < 8; ++n) {
      const int col = 128 * w + 16 * n + li;
#pragma unroll
      for (int r = 0; r < 4; ++r) {
        const int rw = 16 * p + 4 * kh + r;
        ex[(rw & 15) * 1024 + swz_ex(rw, col)] = acc[p][n][r] * (1.0f / FDIM);
      }
    }
    __syncthreads();
    if ((w >> 2) == p) {
#pragma unroll
      for (int t = 0; t < 64; ++t)
        v[t] = ex[(R & 15) * 1024 + swz_ex(R, 64 * li + t)];
    }
    __syncthreads();
  }

  sort1024_desc(v, li);

  __syncthreads();
#pragma unroll
  for (int gp = 0; gp < 2; ++gp) {
    if ((w >> 2) == gp) {
#pragma unroll
      for (int t = 0; t < 64; ++t)
        ex[(R & 15) * 1024 + swz_ex(R, 64 * li + t)] = v[t];
    }
    __syncthreads();
    if ((w >> 2) == gp) {
#pragma unroll
      for (int rp = 0; rp < 4; ++rp) {
        const int Rr = 4 * w + rp;
        float ov[4];
#pragma unroll
        for (int q = 0; q < 4; ++q) {
          const int s = rank_of(4 * lane + q);
          ov[q] = ex[(Rr & 15) * 1024 + swz_ex(Rr, s)];
        }
        float* op = out + (size_t)(b * NMAPS + M0 + Rr) * NPOOL;
        *(float4*)(op + 4 * lane) = make_float4(ov[0], ov[1], ov[2], ov[3]);
      }
    }
    __syncthreads();
  }
}

extern "C" void kernel_launch(void* const* d_in, const int* in_sizes, int n_in,
                              void* d_out, int out_size, void* d_ws, size_t ws_size,
                              hipStream_t stream) {
  const float* x = (const float*)d_in[0];
  float* out = (float*)d_out;
  const size_t bf16_bytes = (size_t)NB * NMAPS * FDIM * sizeof(unsigned short);  // 32 MiB

  if (ws_size >= bf16_bytes) {
    unsigned short* xp = (unsigned short*)d_ws;
    convert_perm_kernel<<<dim3((NB * NMAPS * FDIM) / (256 * 8)), dim3(256), 0, stream>>>(x, xp);
    fused_kernel<<<dim3(NB * 32), dim3(512), 0, stream>>>(xp, out);
  } else {
    corr_pool_kernel<<<dim3(NB * 32), dim3(512), 0, stream>>>(x, out);
  }
}

// Round 11
// 143.687 us; speedup vs baseline: 1.8873x; 1.1758x over previous
//
#include <hip/hip_runtime.h>

#define NB    32
#define NMAPS 1024
#define FDIM  512
#define NPOOL 256

typedef short  bf16x8 __attribute__((ext_vector_type(8)));
typedef float  f32x4  __attribute__((ext_vector_type(4)));

// f32 -> bf16 round-to-nearest-even
__device__ __forceinline__ unsigned short f2bf(float f) {
  unsigned int u = __float_as_uint(f);
  return (unsigned short)((u + 0x7fffu + ((u >> 16) & 1u)) >> 16);
}

// 16B-chunk XOR swizzle within a 1024-float row (256 chunks); involution.
__device__ __forceinline__ int swz(int c) { return c ^ ((c >> 3) & 7); }

// exact ranks: round(1 + o*1022/255) = (765 + 2044*o) / 510  (integer div)
__device__ __forceinline__ int rank_of(int o) { return (765 + 2044 * o) / 510; }

// ---------------- convert to FRAGMENT-MAJOR bf16 layout, PRE-SCALED by
// 1/sqrt(512) = 2^-4.5 so that Gram products come out already divided by 512.
// Xp chunk index (((b*64+g)*64+kc)*16+li)*8+e  holds  X[b][16g+li][8kc+e]*s
__global__ __launch_bounds__(256) void convert_perm_kernel(const float* __restrict__ x,
                                                           unsigned short* __restrict__ xp) {
  const float s = 0.044194173824159216f;          // 2^-4.5
  const int T  = blockIdx.x * 256 + threadIdx.x;  // (b,g,kc,li)
  const int li = T & 15;
  const int kc = (T >> 4) & 63;
  const int g  = (T >> 10) & 63;
  const int b  = T >> 16;
  const float* src = x + ((size_t)((b * 64 + g) * 16 + li) * FDIM + kc * 8);
  const float4 p = *(const float4*)src;
  const float4 q = *(const float4*)(src + 4);
  uint4 o;
  o.x = (unsigned)f2bf(p.x * s) | ((unsigned)f2bf(p.y * s) << 16);
  o.y = (unsigned)f2bf(p.z * s) | ((unsigned)f2bf(p.w * s) << 16);
  o.z = (unsigned)f2bf(q.x * s) | ((unsigned)f2bf(q.y * s) << 16);
  o.w = (unsigned)f2bf(q.z * s) | ((unsigned)f2bf(q.w * s) << 16);
  *(uint4*)(xp + (size_t)T * 8) = o;
}

// ---------------- descending bitonic sort, round-10-proven geometry
// (e = 32*ll + t, ll = lane&31, 32 elems/lane) and sign-flip encoding for
// levels k>=32 (proven r10). New this round (pipe micro-opts only):
//   * cross CE in 2 ops: v = ((v<o) != high) ? o : v   (cmp + cndmask)
//   * jl=1,2 partner fetch via DPP quad_perm (VALU pipe, no DS)
__device__ __forceinline__ void sort32e(float (&v)[32], const int ll) {
  // ---- levels kb=1..4: in-lane, directions compile-time (e&k = t&k)
#pragma unroll
  for (int kb = 1; kb <= 4; ++kb) {
    const int k = 1 << kb;
#pragma unroll
    for (int jb = 3; jb >= 0; --jb) {
      if (jb >= kb) continue;                 // folds at compile time
      const int j = 1 << jb;
#pragma unroll
      for (int t = 0; t < 32; ++t) {
        if (t & j) continue;
        const int u = t | j;
        const float a0 = v[t], b0 = v[u];
        if ((t & k) != 0) { v[t] = fminf(a0, b0); v[u] = fmaxf(a0, b0); }
        else              { v[t] = fmaxf(a0, b0); v[u] = fminf(a0, b0); }
      }
    }
  }
  // ---- levels kb=5..10 with sign-flip encoding (delta-XOR between levels)
  unsigned curM = 0;
#pragma unroll
  for (int kb = 5; kb <= 10; ++kb) {
    const int k = 1 << kb;
    const unsigned m = (kb == 10) ? 0u : ((ll & (k >> 5)) ? 0x80000000u : 0u);
    const unsigned d = curM ^ m;
#pragma unroll
    for (int t = 0; t < 32; ++t)
      v[t] = __int_as_float(__float_as_int(v[t]) ^ (int)d);
    curM = m;
    // cross stages (jb=9..5, jb<kb): low lane keeps max_enc, high keeps min_enc
#pragma unroll
    for (int jb = 9; jb >= 5; --jb) {
      if (jb >= kb) continue;
      const int jl = 1 << (jb - 5);
      const bool high = (ll & jl) != 0;
#pragma unroll
      for (int t = 0; t < 32; ++t) {
        float o;
        if (jl == 1)
          o = __int_as_float(__builtin_amdgcn_mov_dpp(__float_as_int(v[t]),
                                                      0xB1, 0xF, 0xF, true));  // quad [1,0,3,2]
        else if (jl == 2)
          o = __int_as_float(__builtin_amdgcn_mov_dpp(__float_as_int(v[t]),
                                                      0x4E, 0xF, 0xF, true));  // quad [2,3,0,1]
        else
          o = __shfl_xor(v[t], jl, 64);
        v[t] = ((v[t] < o) != high) ? o : v[t];   // 2-op CE; ties safe (equal values)
      }
    }
    // in-lane stages jb=4..0: uniform (low=max, high=min) in encoded space
#pragma unroll
    for (int jb = 4; jb >= 0; --jb) {
      const int j = 1 << jb;
#pragma unroll
      for (int t = 0; t < 32; ++t) {
        if (t & j) continue;
        const int u = t | j;
        const float a0 = v[t], b0 = v[u];
        v[t] = fmaxf(a0, b0);
        v[u] = fminf(a0, b0);
      }
    }
  }
  // curM == 0 after kb=10: values back in plain encoding.
}

// ---------------- FUSED: GEMM(32x1024 tile, MFMA) -> LDS exchange -> sort -> ranks
// (structure byte-identical to the round-10 passing kernel; only the scale
//  mul is removed from the exchange writes — folded into convert)
__global__ __launch_bounds__(512, 4) void fused_kernel(const unsigned short* __restrict__ xp,
                                                       float* __restrict__ out) {
  __shared__ float ex[16 * 1024];   // 64 KiB -> 2 blocks/CU

  const int bid = blockIdx.x;                    // 1024 blocks
  const int wk  = (bid & 7) * 128 + (bid >> 3);  // bijective XCD swizzle
  const int b   = wk >> 5;                       // batch: 4 per XCD
  const int mt  = wk & 31;
  const int M0  = mt * 32;

  const int tid  = threadIdx.x;
  const int lane = tid & 63;
  const int w    = tid >> 6;      // 8 waves; wave owns cols [128w, 128w+128)
  const int li   = lane & 15;
  const int ll   = lane & 31;
  const int h    = lane >> 5;
  const int kh   = lane >> 4;
  const int rloc = 2 * w + h;     // ex row this lane sorts (0..15)

  const unsigned short* __restrict__ Xp = xp + (size_t)b * (NMAPS * FDIM);

  // ================= GEMM phase =================
  f32x4 acc0[8], acc1[8];         // local rows 0..15 / 16..31
#pragma unroll
  for (int n = 0; n < 8; ++n) {
    acc0[n] = (f32x4){0.f, 0.f, 0.f, 0.f};
    acc1[n] = (f32x4){0.f, 0.f, 0.f, 0.f};
  }

  const unsigned short* pA = Xp + (size_t)(2 * mt) * 8192 + lane * 8;  // 8192 = 16*512
  const unsigned short* pB = Xp + (size_t)(8 * w) * 8192 + lane * 8;

  for (int kc0 = 0; kc0 < 64; kc0 += 4) {   // K step 32 (4 chunks of 8)
    const bf16x8 A0 = *(const bf16x8*)(pA + kc0 * 128);
    const bf16x8 A1 = *(const bf16x8*)(pA + 8192 + kc0 * 128);
#pragma unroll
    for (int half = 0; half < 2; ++half) {   // limit live B-frags to 4
      bf16x8 B[4];
#pragma unroll
      for (int n = 0; n < 4; ++n)
        B[n] = *(const bf16x8*)(pB + (size_t)(4 * half + n) * 8192 + kc0 * 128);
#pragma unroll
      for (int n = 0; n < 4; ++n) {
        if (half == 0) {
          acc0[n] = __builtin_amdgcn_mfma_f32_16x16x32_bf16(A0, B[n], acc0[n], 0, 0, 0);
          acc1[n] = __builtin_amdgcn_mfma_f32_16x16x32_bf16(A1, B[n], acc1[n], 0, 0, 0);
        } else {
          acc0[4 + n] = __builtin_amdgcn_mfma_f32_16x16x32_bf16(A0, B[n], acc0[4 + n], 0, 0, 0);
          acc1[4 + n] = __builtin_amdgcn_mfma_f32_16x16x32_bf16(A1, B[n], acc1[4 + n], 0, 0, 0);
        }
      }
    }
  }

  // ================= exchange phase (round-10 proven) =================
  float v0[32], v1[32];

  // ---- phase 0: rows 0..15
#pragma unroll
  for (int n = 0; n < 8; ++n) {
    const int cw = 32 * w + 4 * n + (li >> 2);   // 16B chunk of col
    const int q  = li & 3;
#pragma unroll
    for (int r = 0; r < 4; ++r)
      ex[(4 * kh + r) * 1024 + swz(cw) * 4 + q] = acc0[n][r];
  }
  __syncthreads();
#pragma unroll
  for (int i = 0; i < 8; ++i) {
    const float4 t4 = *(const float4*)(ex + rloc * 1024 + swz(8 * ll + i) * 4);
    v0[4 * i + 0] = t4.x; v0[4 * i + 1] = t4.y;
    v0[4 * i + 2] = t4.z; v0[4 * i + 3] = t4.w;
  }
  __syncthreads();

  // ---- phase 1: rows 16..31
#pragma unroll
  for (int n = 0; n < 8; ++n) {
    const int cw = 32 * w + 4 * n + (li >> 2);
    const int q  = li & 3;
#pragma unroll
    for (int r = 0; r < 4; ++r)
      ex[(4 * kh + r) * 1024 + swz(cw) * 4 + q] = acc1[n][r];
  }
  __syncthreads();
#pragma unroll
  for (int i = 0; i < 8; ++i) {
    const float4 t4 = *(const float4*)(ex + rloc * 1024 + swz(8 * ll + i) * 4);
    v1[4 * i + 0] = t4.x; v1[4 * i + 1] = t4.y;
    v1[4 * i + 2] = t4.z; v1[4 * i + 3] = t4.w;
  }
  // no further barriers: each wave now only touches ex rows 2w, 2w+1 (own region)

  // ================= sort + rank gather, phase 0 rows =================
  sort32e(v0, ll);
#pragma unroll
  for (int i = 0; i < 8; ++i)
    *(float4*)(ex + rloc * 1024 + swz(8 * ll + i) * 4) =
        make_float4(v0[4 * i + 0], v0[4 * i + 1], v0[4 * i + 2], v0[4 * i + 3]);
#pragma unroll
  for (int h2 = 0; h2 < 2; ++h2) {
    const float* sb = ex + (2 * w + h2) * 1024;
    float ov[4];
#pragma unroll
    for (int q = 0; q < 4; ++q) {
      const int s = rank_of(4 * lane + q);
      ov[q] = sb[swz(s >> 2) * 4 + (s & 3)];
    }
    *(float4*)(out + ((size_t)b * NMAPS + M0 + 2 * w + h2) * NPOOL + 4 * lane) =
        make_float4(ov[0], ov[1], ov[2], ov[3]);
  }

  // ================= sort + rank gather, phase 1 rows =================
  sort32e(v1, ll);
#pragma unroll
  for (int i = 0; i < 8; ++i)
    *(float4*)(ex + rloc * 1024 + swz(8 * ll + i) * 4) =
        make_float4(v1[4 * i + 0], v1[4 * i + 1], v1[4 * i + 2], v1[4 * i + 3]);
#pragma unroll
  for (int h2 = 0; h2 < 2; ++h2) {
    const float* sb = ex + (2 * w + h2) * 1024;
    float ov[4];
#pragma unroll
    for (int q = 0; q < 4; ++q) {
      const int s = rank_of(4 * lane + q);
      ov[q] = sb[swz(s >> 2) * 4 + (s & 3)];
    }
    *(float4*)(out + ((size_t)b * NMAPS + M0 + 16 + 2 * w + h2) * NPOOL + 4 * lane) =
        make_float4(ov[0], ov[1], ov[2], ov[3]);
  }
}

// ================= fallback fused kernel (used only if ws too small) =================
__device__ __forceinline__ bf16x8 ld_frag_f32(const float* p) {
  const float4 a = *(const float4*)p;
  const float4 b = *(const float4*)(p + 4);
  bf16x8 r;
  r[0] = (short)f2bf(a.x); r[1] = (short)f2bf(a.y);
  r[2] = (short)f2bf(a.z); r[3] = (short)f2bf(a.w);
  r[4] = (short)f2bf(b.x); r[5] = (short)f2bf(b.y);
  r[6] = (short)f2bf(b.z); r[7] = (short)f2bf(b.w);
  return r;
}

__device__ __forceinline__ int swz_ex(int row, int col) {
  return col ^ (((col >> 6) & 15) << 1) ^ (row & 1) ^ (((row >> 2) & 1) << 4);
}

__device__ __forceinline__ void sort1024_desc(float (&v)[64], const int li) {
#pragma unroll
  for (int kb = 1; kb <= 10; ++kb) {
    const int k = 1 << kb;
#pragma unroll
    for (int jb = 9; jb >= 0; --jb) {
      if (jb >= kb) continue;
      const int j = 1 << jb;
      if (jb >= 6) {
        const int jl = j >> 6;
        const bool up = (li & (k >> 6)) != 0;
        const bool tm = up == ((li & jl) == 0);
#pragma unroll
        for (int t = 0; t < 64; ++t) {
          const float o  = __shfl_xor(v[t], jl, 64);
          const float mn = fminf(v[t], o);
          const float mx = fmaxf(v[t], o);
          v[t] = tm ? mn : mx;
        }
      } else if (kb <= 5) {
#pragma unroll
        for (int t = 0; t < 64; ++t) {
          if (t & j) continue;
          const int u = t | j;
          const float a0 = v[t], b0 = v[u];
          if ((t & k) != 0) { v[t] = fminf(a0, b0); v[u] = fmaxf(a0, b0); }
          else              { v[t] = fmaxf(a0, b0); v[u] = fminf(a0, b0); }
        }
      } else {
        const bool tm = (li & (k >> 6)) != 0;
#pragma unroll
        for (int t = 0; t < 64; ++t) {
          if (t & j) continue;
          const int u = t | j;
          const float a0 = v[t], b0 = v[u];
          const float mn = fminf(a0, b0), mx = fmaxf(a0, b0);
          v[t] = tm ? mn : mx;
          v[u] = tm ? mx : mn;
        }
      }
    }
  }
}

__global__ __launch_bounds__(512) void corr_pool_kernel(const float* __restrict__ x,
                                                        float* __restrict__ out) {
  __shared__ float ex[16 * 1024];
  const int bid = blockIdx.x;
  const int xcd = bid & 7;
  const int idx = bid >> 3;
  const int b   = xcd + 8 * (idx >> 5);
  const int M0  = (idx & 31) * 32;

  const int tid  = threadIdx.x;
  const int lane = tid & 63;
  const int w    = tid >> 6;
  const int li   = lane & 15;
  const int kh   = lane >> 4;

  const float* __restrict__ Xf = x + (size_t)b * NMAPS * FDIM;

  f32x4 acc[2][8];
#pragma unroll
  for (int a = 0; a < 2; ++a)
#pragma unroll
    for (int n = 0; n < 8; ++n) acc[a][n] = (f32x4){0.f, 0.f, 0.f, 0.f};

#pragma unroll 2
  for (int k0 = 0; k0 < FDIM; k0 += 32) {
    bf16x8 A[2], B[8];
#pragma unroll
    for (int a = 0; a < 2; ++a)
      A[a] = ld_frag_f32(Xf + (M0 + 16 * a + li) * FDIM + k0 + kh * 8);
#pragma unroll
    for (int n = 0; n < 8; ++n)
      B[n] = ld_frag_f32(Xf + (128 * w + 16 * n + li) * FDIM + k0 + kh * 8);
#pragma unroll
    for (int a = 0; a < 2; ++a)
#pragma unroll
      for (int n = 0; n < 8; ++n)
        acc[a][n] = __builtin_amdgcn_mfma_f32_16x16x32_bf16(A[a], B[n], acc[a][n], 0, 0, 0);
  }

  const int R = 4 * w + kh;
  float v[64];
#pragma unroll
  for (int p = 0; p < 2; ++p) {
#pragma unroll
    for (int n = 0; n < 8; ++n) {
      const int col = 128 * w + 16 * n + li;
#pragma unroll
      for (int r = 0; r < 4; ++r) {
        const int rw = 16 * p + 4 * kh + r;
        ex[(rw & 15) * 1024 + swz_ex(rw, col)] = acc[p][n][r] * (1.0f / FDIM);
      }
    }
    __syncthreads();
    if ((w >> 2) == p) {
#pragma unroll
      for (int t = 0; t < 64; ++t)
        v[t] = ex[(R & 15) * 1024 + swz_ex(R, 64 * li + t)];
    }
    __syncthreads();
  }

  sort1024_desc(v, li);

  __syncthreads();
#pragma unroll
  for (int gp = 0; gp < 2; ++gp) {
    if ((w >> 2) == gp) {
#pragma unroll
      for (int t = 0; t < 64; ++t)
        ex[(R & 15) * 1024 + swz_ex(R, 64 * li + t)] = v[t];
    }
    __syncthreads();
    if ((w >> 2) == gp) {
#pragma unroll
      for (int rp = 0; rp < 4; ++rp) {
        const int Rr = 4 * w + rp;
        float ov[4];
#pragma unroll
        for (int q = 0; q < 4; ++q) {
          const int s = rank_of(4 * lane + q);
          ov[q] = ex[(Rr & 15) * 1024 + swz_ex(Rr, s)];
        }
        float* op = out + (size_t)(b * NMAPS + M0 + Rr) * NPOOL;
        *(float4*)(op + 4 * lane) = make_float4(ov[0], ov[1], ov[2], ov[3]);
      }
    }
    __syncthreads();
  }
}

extern "C" void kernel_launch(void* const* d_in, const int* in_sizes, int n_in,
                              void* d_out, int out_size, void* d_ws, size_t ws_size,
                              hipStream_t stream) {
  const float* x = (const float*)d_in[0];
  float* out = (float*)d_out;
  const size_t bf16_bytes = (size_t)NB * NMAPS * FDIM * sizeof(unsigned short);  // 32 MiB

  if (ws_size >= bf16_bytes) {
    unsigned short* xp = (unsigned short*)d_ws;
    convert_perm_kernel<<<dim3((NB * NMAPS * FDIM) / (256 * 8)), dim3(256), 0, stream>>>(x, xp);
    fused_kernel<<<dim3(NB * 32), dim3(512), 0, stream>>>(xp, out);
  } else {
    corr_pool_kernel<<<dim3(NB * 32), dim3(512), 0, stream>>>(x, out);
  }
}

// Round 12
// 137.387 us; speedup vs baseline: 1.9738x; 1.0459x over previous
//
#include <hip/hip_runtime.h>

#define NB    32
#define NMAPS 1024
#define FDIM  512
#define NPOOL 256

typedef short  bf16x8 __attribute__((ext_vector_type(8)));
typedef float  f32x4  __attribute__((ext_vector_type(4)));

// f32 -> bf16 round-to-nearest-even
__device__ __forceinline__ unsigned short f2bf(float f) {
  unsigned int u = __float_as_uint(f);
  return (unsigned short)((u + 0x7fffu + ((u >> 16) & 1u)) >> 16);
}

// 16B-chunk XOR swizzle within a 1024-float row (256 chunks); involution.
__device__ __forceinline__ int swz(int c) { return c ^ ((c >> 3) & 7); }

// exact ranks: round(1 + o*1022/255) = (765 + 2044*o) / 510  (integer div)
__device__ __forceinline__ int rank_of(int o) { return (765 + 2044 * o) / 510; }

// ---------------- convert to FRAGMENT-MAJOR bf16 layout, PRE-SCALED by
// 1/sqrt(512) = 2^-4.5 so that Gram products come out already divided by 512.
// Xp chunk index (((b*64+g)*64+kc)*16+li)*8+e  holds  X[b][16g+li][8kc+e]*s
__global__ __launch_bounds__(256) void convert_perm_kernel(const float* __restrict__ x,
                                                           unsigned short* __restrict__ xp) {
  const float s = 0.044194173824159216f;          // 2^-4.5
  const int T  = blockIdx.x * 256 + threadIdx.x;  // (b,g,kc,li)
  const int li = T & 15;
  const int kc = (T >> 4) & 63;
  const int g  = (T >> 10) & 63;
  const int b  = T >> 16;
  const float* src = x + ((size_t)((b * 64 + g) * 16 + li) * FDIM + kc * 8);
  const float4 p = *(const float4*)src;
  const float4 q = *(const float4*)(src + 4);
  uint4 o;
  o.x = (unsigned)f2bf(p.x * s) | ((unsigned)f2bf(p.y * s) << 16);
  o.y = (unsigned)f2bf(p.z * s) | ((unsigned)f2bf(p.w * s) << 16);
  o.z = (unsigned)f2bf(q.x * s) | ((unsigned)f2bf(q.y * s) << 16);
  o.w = (unsigned)f2bf(q.z * s) | ((unsigned)f2bf(q.w * s) << 16);
  *(uint4*)(xp + (size_t)T * 8) = o;
}

// cross-lane xor partner within 32-lane groups:
// jl=1,2 via DPP quad_perm (VALU, proven r11); jl=4,8,16 via ds_swizzle
// immediates (BitMode xor patterns; movement == __shfl_xor, proven r8==r9).
__device__ __forceinline__ float xsh(float x, const int jl) {
  const int xi = __float_as_int(x);
  int r;
  if (jl == 1)      r = __builtin_amdgcn_mov_dpp(xi, 0xB1, 0xF, 0xF, true);  // quad [1,0,3,2]
  else if (jl == 2) r = __builtin_amdgcn_mov_dpp(xi, 0x4E, 0xF, 0xF, true);  // quad [2,3,0,1]
  else if (jl == 4) r = __builtin_amdgcn_ds_swizzle(xi, 0x101F);             // xor 4
  else if (jl == 8) r = __builtin_amdgcn_ds_swizzle(xi, 0x201F);             // xor 8
  else              r = __builtin_amdgcn_ds_swizzle(xi, 0x401F);             // xor 16
  return __int_as_float(r);
}

// ---------------- descending bitonic sort, round-11-proven network, applied
// to TWO independent rows (A,B) stage-interleaved: while one array's DS
// cross-fetches are in flight, the other's VALU CEs issue (covers lgkmcnt).
// Geometry: e = 32*ll + t, ll = lane&31, 32 elems/lane; sign-flip encoding
// for levels k>=32; cross CE = 2 ops: v = ((v<o)!=high) ? o : v.
__device__ __forceinline__ void sort32e2(float (&A)[32], float (&B)[32], const int ll) {
  // ---- levels kb=1..4: in-lane, directions compile-time (e&k = t&k)
#pragma unroll
  for (int kb = 1; kb <= 4; ++kb) {
    const int k = 1 << kb;
#pragma unroll
    for (int jb = 3; jb >= 0; --jb) {
      if (jb >= kb) continue;                 // folds at compile time
      const int j = 1 << jb;
#pragma unroll
      for (int t = 0; t < 32; ++t) {
        if (t & j) continue;
        const int u = t | j;
        {
          const float a0 = A[t], b0 = A[u];
          if ((t & k) != 0) { A[t] = fminf(a0, b0); A[u] = fmaxf(a0, b0); }
          else              { A[t] = fmaxf(a0, b0); A[u] = fminf(a0, b0); }
        }
        {
          const float a0 = B[t], b0 = B[u];
          if ((t & k) != 0) { B[t] = fminf(a0, b0); B[u] = fmaxf(a0, b0); }
          else              { B[t] = fmaxf(a0, b0); B[u] = fminf(a0, b0); }
        }
      }
    }
  }
  // ---- levels kb=5..10 with sign-flip encoding (delta-XOR between levels)
  unsigned curM = 0;
#pragma unroll
  for (int kb = 5; kb <= 10; ++kb) {
    const int k = 1 << kb;
    const unsigned m = (kb == 10) ? 0u : ((ll & (k >> 5)) ? 0x80000000u : 0u);
    const unsigned d = curM ^ m;
#pragma unroll
    for (int t = 0; t < 32; ++t) {
      A[t] = __int_as_float(__float_as_int(A[t]) ^ (int)d);
      B[t] = __int_as_float(__float_as_int(B[t]) ^ (int)d);
    }
    curM = m;
    // cross stages: low lane keeps max_enc, high keeps min_enc (2-op CE)
#pragma unroll
    for (int jb = 9; jb >= 5; --jb) {
      if (jb >= kb) continue;
      const int jl = 1 << (jb - 5);
      const bool high = (ll & jl) != 0;
#pragma unroll
      for (int t = 0; t < 32; ++t) {
        const float oa = xsh(A[t], jl);
        const float ob = xsh(B[t], jl);
        A[t] = ((A[t] < oa) != high) ? oa : A[t];
        B[t] = ((B[t] < ob) != high) ? ob : B[t];
      }
    }
    // in-lane stages jb=4..0: uniform (low=max, high=min) in encoded space
#pragma unroll
    for (int jb = 4; jb >= 0; --jb) {
      const int j = 1 << jb;
#pragma unroll
      for (int t = 0; t < 32; ++t) {
        if (t & j) continue;
        const int u = t | j;
        {
          const float a0 = A[t], b0 = A[u];
          A[t] = fmaxf(a0, b0);
          A[u] = fminf(a0, b0);
        }
        {
          const float a0 = B[t], b0 = B[u];
          B[t] = fmaxf(a0, b0);
          B[u] = fminf(a0, b0);
        }
      }
    }
  }
  // curM == 0 after kb=10: values back in plain encoding.
}

// ---------------- FUSED: GEMM(32x1024 tile, MFMA) -> LDS exchange -> sort -> ranks
// (round-11 structure; sorts interleaved, rank addresses hoisted)
__global__ __launch_bounds__(512, 4) void fused_kernel(const unsigned short* __restrict__ xp,
                                                       float* __restrict__ out) {
  __shared__ float ex[16 * 1024];   // 64 KiB -> 2 blocks/CU

  const int bid = blockIdx.x;                    // 1024 blocks
  const int wk  = (bid & 7) * 128 + (bid >> 3);  // bijective XCD swizzle
  const int b   = wk >> 5;                       // batch: 4 per XCD
  const int mt  = wk & 31;
  const int M0  = mt * 32;

  const int tid  = threadIdx.x;
  const int lane = tid & 63;
  const int w    = tid >> 6;      // 8 waves; wave owns cols [128w, 128w+128)
  const int li   = lane & 15;
  const int ll   = lane & 31;
  const int h    = lane >> 5;
  const int kh   = lane >> 4;
  const int rloc = 2 * w + h;     // ex row this lane sorts (0..15)

  const unsigned short* __restrict__ Xp = xp + (size_t)b * (NMAPS * FDIM);

  // ================= GEMM phase =================
  f32x4 acc0[8], acc1[8];         // local rows 0..15 / 16..31
#pragma unroll
  for (int n = 0; n < 8; ++n) {
    acc0[n] = (f32x4){0.f, 0.f, 0.f, 0.f};
    acc1[n] = (f32x4){0.f, 0.f, 0.f, 0.f};
  }

  const unsigned short* pA = Xp + (size_t)(2 * mt) * 8192 + lane * 8;  // 8192 = 16*512
  const unsigned short* pB = Xp + (size_t)(8 * w) * 8192 + lane * 8;

  for (int kc0 = 0; kc0 < 64; kc0 += 4) {   // K step 32 (4 chunks of 8)
    const bf16x8 A0 = *(const bf16x8*)(pA + kc0 * 128);
    const bf16x8 A1 = *(const bf16x8*)(pA + 8192 + kc0 * 128);
#pragma unroll
    for (int half = 0; half < 2; ++half) {   // limit live B-frags to 4
      bf16x8 B[4];
#pragma unroll
      for (int n = 0; n < 4; ++n)
        B[n] = *(const bf16x8*)(pB + (size_t)(4 * half + n) * 8192 + kc0 * 128);
#pragma unroll
      for (int n = 0; n < 4; ++n) {
        if (half == 0) {
          acc0[n] = __builtin_amdgcn_mfma_f32_16x16x32_bf16(A0, B[n], acc0[n], 0, 0, 0);
          acc1[n] = __builtin_amdgcn_mfma_f32_16x16x32_bf16(A1, B[n], acc1[n], 0, 0, 0);
        } else {
          acc0[4 + n] = __builtin_amdgcn_mfma_f32_16x16x32_bf16(A0, B[n], acc0[4 + n], 0, 0, 0);
          acc1[4 + n] = __builtin_amdgcn_mfma_f32_16x16x32_bf16(A1, B[n], acc1[4 + n], 0, 0, 0);
        }
      }
    }
  }

  // ================= exchange phase (round-10/11 proven) =================
  float v0[32], v1[32];

  // ---- phase 0: rows 0..15
#pragma unroll
  for (int n = 0; n < 8; ++n) {
    const int cw = 32 * w + 4 * n + (li >> 2);   // 16B chunk of col
    const int q  = li & 3;
#pragma unroll
    for (int r = 0; r < 4; ++r)
      ex[(4 * kh + r) * 1024 + swz(cw) * 4 + q] = acc0[n][r];
  }
  __syncthreads();
#pragma unroll
  for (int i = 0; i < 8; ++i) {
    const float4 t4 = *(const float4*)(ex + rloc * 1024 + swz(8 * ll + i) * 4);
    v0[4 * i + 0] = t4.x; v0[4 * i + 1] = t4.y;
    v0[4 * i + 2] = t4.z; v0[4 * i + 3] = t4.w;
  }
  __syncthreads();

  // ---- phase 1: rows 16..31
#pragma unroll
  for (int n = 0; n < 8; ++n) {
    const int cw = 32 * w + 4 * n + (li >> 2);
    const int q  = li & 3;
#pragma unroll
    for (int r = 0; r < 4; ++r)
      ex[(4 * kh + r) * 1024 + swz(cw) * 4 + q] = acc1[n][r];
  }
  __syncthreads();
#pragma unroll
  for (int i = 0; i < 8; ++i) {
    const float4 t4 = *(const float4*)(ex + rloc * 1024 + swz(8 * ll + i) * 4);
    v1[4 * i + 0] = t4.x; v1[4 * i + 1] = t4.y;
    v1[4 * i + 2] = t4.z; v1[4 * i + 3] = t4.w;
  }
  __syncthreads();   // all reads done; slots become wave-private from here on

  // ================= interleaved in-register sort of both rows ==========
  sort32e2(v0, v1, ll);

  // hoisted rank-gather LDS offsets (uniform per lane)
  int ra[4];
#pragma unroll
  for (int q = 0; q < 4; ++q) {
    const int s = rank_of(4 * lane + q);
    ra[q] = swz(s >> 2) * 4 + (s & 3);
  }

  // ================= dump + rank gather, phase 0 rows =================
#pragma unroll
  for (int i = 0; i < 8; ++i)
    *(float4*)(ex + rloc * 1024 + swz(8 * ll + i) * 4) =
        make_float4(v0[4 * i + 0], v0[4 * i + 1], v0[4 * i + 2], v0[4 * i + 3]);
#pragma unroll
  for (int h2 = 0; h2 < 2; ++h2) {
    const float* sb = ex + (2 * w + h2) * 1024;
    float ov[4];
#pragma unroll
    for (int q = 0; q < 4; ++q) ov[q] = sb[ra[q]];
    *(float4*)(out + ((size_t)b * NMAPS + M0 + 2 * w + h2) * NPOOL + 4 * lane) =
        make_float4(ov[0], ov[1], ov[2], ov[3]);
  }

  // ================= dump + rank gather, phase 1 rows =================
  // (write-after-read to same wave-private slots: in-wave LDS ordering, proven r10/r11)
#pragma unroll
  for (int i = 0; i < 8; ++i)
    *(float4*)(ex + rloc * 1024 + swz(8 * ll + i) * 4) =
        make_float4(v1[4 * i + 0], v1[4 * i + 1], v1[4 * i + 2], v1[4 * i + 3]);
#pragma unroll
  for (int h2 = 0; h2 < 2; ++h2) {
    const float* sb = ex + (2 * w + h2) * 1024;
    float ov[4];
#pragma unroll
    for (int q = 0; q < 4; ++q) ov[q] = sb[ra[q]];
    *(float4*)(out + ((size_t)b * NMAPS + M0 + 16 + 2 * w + h2) * NPOOL + 4 * lane) =
        make_float4(ov[0], ov[1], ov[2], ov[3]);
  }
}

// ================= fallback fused kernel (used only if ws too small) =================
__device__ __forceinline__ bf16x8 ld_frag_f32(const float* p) {
  const float4 a = *(const float4*)p;
  const float4 b = *(const float4*)(p + 4);
  bf16x8 r;
  r[0] = (short)f2bf(a.x); r[1] = (short)f2bf(a.y);
  r[2] = (short)f2bf(a.z); r[3] = (short)f2bf(a.w);
  r[4] = (short)f2bf(b.x); r[5] = (short)f2bf(b.y);
  r[6] = (short)f2bf(b.z); r[7] = (short)f2bf(b.w);
  return r;
}

__device__ __forceinline__ int swz_ex(int row, int col) {
  return col ^ (((col >> 6) & 15) << 1) ^ (row & 1) ^ (((row >> 2) & 1) << 4);
}

__device__ __forceinline__ void sort1024_desc(float (&v)[64], const int li) {
#pragma unroll
  for (int kb = 1; kb <= 10; ++kb) {
    const int k = 1 << kb;
#pragma unroll
    for (int jb = 9; jb >= 0; --jb) {
      if (jb >= kb) continue;
      const int j = 1 << jb;
      if (jb >= 6) {
        const int jl = j >> 6;
        const bool up = (li & (k >> 6)) != 0;
        const bool tm = up == ((li & jl) == 0);
#pragma unroll
        for (int t = 0; t < 64; ++t) {
          const float o  = __shfl_xor(v[t], jl, 64);
          const float mn = fminf(v[t], o);
          const float mx = fmaxf(v[t], o);
          v[t] = tm ? mn : mx;
        }
      } else if (kb <= 5) {
#pragma unroll
        for (int t = 0; t < 64; ++t) {
          if (t & j) continue;
          const int u = t | j;
          const float a0 = v[t], b0 = v[u];
          if ((t & k) != 0) { v[t] = fminf(a0, b0); v[u] = fmaxf(a0, b0); }
          else              { v[t] = fmaxf(a0, b0); v[u] = fminf(a0, b0); }
        }
      } else {
        const bool tm = (li & (k >> 6)) != 0;
#pragma unroll
        for (int t = 0; t < 64; ++t) {
          if (t & j) continue;
          const int u = t | j;
          const float a0 = v[t], b0 = v[u];
          const float mn = fminf(a0, b0), mx = fmaxf(a0, b0);
          v[t] = tm ? mn : mx;
          v[u] = tm ? mx : mn;
        }
      }
    }
  }
}

__global__ __launch_bounds__(512) void corr_pool_kernel(const float* __restrict__ x,
                                                        float* __restrict__ out) {
  __shared__ float ex[16 * 1024];
  const int bid = blockIdx.x;
  const int xcd = bid & 7;
  const int idx = bid >> 3;
  const int b   = xcd + 8 * (idx >> 5);
  const int M0  = (idx & 31) * 32;

  const int tid  = threadIdx.x;
  const int lane = tid & 63;
  const int w    = tid >> 6;
  const int li   = lane & 15;
  const int kh   = lane >> 4;

  const float* __restrict__ Xf = x + (size_t)b * NMAPS * FDIM;

  f32x4 acc[2][8];
#pragma unroll
  for (int a = 0; a < 2; ++a)
#pragma unroll
    for (int n = 0; n < 8; ++n) acc[a][n] = (f32x4){0.f, 0.f, 0.f, 0.f};

#pragma unroll 2
  for (int k0 = 0; k0 < FDIM; k0 += 32) {
    bf16x8 A[2], B[8];
#pragma unroll
    for (int a = 0; a < 2; ++a)
      A[a] = ld_frag_f32(Xf + (M0 + 16 * a + li) * FDIM + k0 + kh * 8);
#pragma unroll
    for (int n = 0; n < 8; ++n)
      B[n] = ld_frag_f32(Xf + (128 * w + 16 * n + li) * FDIM + k0 + kh * 8);
#pragma unroll
    for (int a = 0; a < 2; ++a)
#pragma unroll
      for (int n = 0; n < 8; ++n)
        acc[a][n] = __builtin_amdgcn_mfma_f32_16x16x32_bf16(A[a], B[n], acc[a][n], 0, 0, 0);
  }

  const int R = 4 * w + kh;
  float v[64];
#pragma unroll
  for (int p = 0; p < 2; ++p) {
#pragma unroll
    for (int n = 0; n < 8; ++n) {
      const int col = 128 * w + 16 * n + li;
#pragma unroll
      for (int r = 0; r < 4; ++r) {
        const int rw = 16 * p + 4 * kh + r;
        ex[(rw & 15) * 1024 + swz_ex(rw, col)] = acc[p][n][r] * (1.0f / FDIM);
      }
    }
    __syncthreads();
    if ((w >> 2) == p) {
#pragma unroll
      for (int t = 0; t < 64; ++t)
        v[t] = ex[(R & 15) * 1024 + swz_ex(R, 64 * li + t)];
    }
    __syncthreads();
  }

  sort1024_desc(v, li);

  __syncthreads();
#pragma unroll
  for (int gp = 0; gp < 2; ++gp) {
    if ((w >> 2) == gp) {
#pragma unroll
      for (int t = 0; t < 64; ++t)
        ex[(R & 15) * 1024 + swz_ex(R, 64 * li + t)] = v[t];
    }
    __syncthreads();
    if ((w >> 2) == gp) {
#pragma unroll
      for (int rp = 0; rp < 4; ++rp) {
        const int Rr = 4 * w + rp;
        float ov[4];
#pragma unroll
        for (int q = 0; q < 4; ++q) {
          const int s = rank_of(4 * lane + q);
          ov[q] = ex[(Rr & 15) * 1024 + swz_ex(Rr, s)];
        }
        float* op = out + (size_t)(b * NMAPS + M0 + Rr) * NPOOL;
        *(float4*)(op + 4 * lane) = make_float4(ov[0], ov[1], ov[2], ov[3]);
      }
    }
    __syncthreads();
  }
}

extern "C" void kernel_launch(void* const* d_in, const int* in_sizes, int n_in,
                              void* d_out, int out_size, void* d_ws, size_t ws_size,
                              hipStream_t stream) {
  const float* x = (const float*)d_in[0];
  float* out = (float*)d_out;
  const size_t bf16_bytes = (size_t)NB * NMAPS * FDIM * sizeof(unsigned short);  // 32 MiB

  if (ws_size >= bf16_bytes) {
    unsigned short* xp = (unsigned short*)d_ws;
    convert_perm_kernel<<<dim3((NB * NMAPS * FDIM) / (256 * 8)), dim3(256), 0, stream>>>(x, xp);
    fused_kernel<<<dim3(NB * 32), dim3(512), 0, stream>>>(xp, out);
  } else {
    corr_pool_kernel<<<dim3(NB * 32), dim3(512), 0, stream>>>(x, out);
  }
}